// Round 6
// baseline (101.049 us; speedup 1.0000x reference)
//
#include <hip/hip_runtime.h>

namespace {

constexpr int K     = 6;
constexpr int KK    = 36;   // K*K
constexpr int DF    = 8;    // D_FEAT
constexpr int DLAT  = 16;
constexpr int NS    = 5;
constexpr int B     = 131072;
constexpr int M     = NS * B;           // 655360 (sample, batch) pairs
constexpr float EPS = 1e-20f;

// ---------------------------------------------------------------------------
// Kernel A (per-b): exp_la[b][36] = exp(latent[b]@W_sink + b_sink)  -> ws
// Also computes masknet softmax (reads latent once, saves a launch).
// One thread per b; W/b indices compile-time -> wave-uniform scalar loads.
// ---------------------------------------------------------------------------
__global__ __launch_bounds__(256) void prep_kernel(
    const float* __restrict__ latent,
    const float* __restrict__ W_sink,
    const float* __restrict__ b_sink,
    const float* __restrict__ W_mask,
    const float* __restrict__ b_mask,
    float* __restrict__ ela,        // [B][KK]
    float* __restrict__ stopping)   // [B][K]
{
    const int b = blockIdx.x * 256 + threadIdx.x;   // grid is exactly B/256

    float lat[DLAT];
    const float4* lat4 = reinterpret_cast<const float4*>(latent + (size_t)b * DLAT);
    #pragma unroll
    for (int k = 0; k < 4; ++k) {
        float4 v = lat4[k];
        lat[k*4+0] = v.x; lat[k*4+1] = v.y; lat[k*4+2] = v.z; lat[k*4+3] = v.w;
    }

    // sinknet matvec (576 FMA) — now once per b instead of 5x
    float la[KK];
    #pragma unroll
    for (int i = 0; i < KK; ++i) la[i] = b_sink[i];
    #pragma unroll
    for (int k = 0; k < DLAT; ++k) {
        const float lv = lat[k];
        #pragma unroll
        for (int i = 0; i < KK; ++i)
            la[i] = fmaf(lv, W_sink[k*KK + i], la[i]);
    }

    float4* e4 = reinterpret_cast<float4*>(ela + (size_t)b * KK);
    #pragma unroll
    for (int q = 0; q < 9; ++q) {
        float4 v;
        v.x = __expf(la[q*4+0]); v.y = __expf(la[q*4+1]);
        v.z = __expf(la[q*4+2]); v.w = __expf(la[q*4+3]);
        e4[q] = v;
    }

    // masknet: softmax(latent @ W_mask + b_mask)
    float v[K];
    #pragma unroll
    for (int i = 0; i < K; ++i) v[i] = b_mask[i];
    #pragma unroll
    for (int k = 0; k < DLAT; ++k) {
        const float lv = lat[k];
        #pragma unroll
        for (int i = 0; i < K; ++i)
            v[i] = fmaf(lv, W_mask[k*K + i], v[i]);
    }
    float mx = v[0];
    #pragma unroll
    for (int i = 1; i < K; ++i) mx = fmaxf(mx, v[i]);
    float sum = 0.f;
    #pragma unroll
    for (int i = 0; i < K; ++i) { v[i] = __expf(v[i] - mx); sum += v[i]; }
    const float inv = __builtin_amdgcn_rcpf(sum);
    float2* o2 = reinterpret_cast<float2*>(stopping + (size_t)b * K);
    o2[0] = make_float2(v[0]*inv, v[1]*inv);
    o2[1] = make_float2(v[2]*inv, v[3]*inv);
    o2[2] = make_float2(v[4]*inv, v[5]*inv);
}

// ---------------------------------------------------------------------------
// Kernel B (per (s,b), batch-major): p = exp_la * rcp(EPS - log(u+EPS)),
// 5x exp-domain Sinkhorn (row/col sum-normalize), then seq^T gather-matmul.
// exp(la - log(Z)) == exp_la / Z exactly; Z in [EPS, ~46] -> p <= ~1e24, f32-safe.
// 5 adjacent lanes share b -> exp_la/seq loads L1-broadcast.
// ---------------------------------------------------------------------------
__global__ __launch_bounds__(256) void sink_kernel(
    const float* __restrict__ seq,
    const float* __restrict__ noise,
    const float* __restrict__ ela,
    float* __restrict__ out)
{
    const int m = blockIdx.x * 256 + threadIdx.x;
    const int b = (int)((unsigned)m / 5u);
    const int s = m - b * 5;
    const size_t row = (size_t)s * B + b;          // noise / out row

    float p[KK];
    {
        const float4* e4 = reinterpret_cast<const float4*>(ela + (size_t)b * KK);
        const float4* n4 = reinterpret_cast<const float4*>(noise + row * KK);
        #pragma unroll
        for (int q = 0; q < 9; ++q) {
            float4 e = e4[q];
            float4 u = n4[q];
            p[q*4+0] = e.x * __builtin_amdgcn_rcpf(EPS - __logf(u.x + EPS));
            p[q*4+1] = e.y * __builtin_amdgcn_rcpf(EPS - __logf(u.y + EPS));
            p[q*4+2] = e.z * __builtin_amdgcn_rcpf(EPS - __logf(u.z + EPS));
            p[q*4+3] = e.w * __builtin_amdgcn_rcpf(EPS - __logf(u.w + EPS));
        }
    }

    #pragma unroll
    for (int it = 0; it < 5; ++it) {
        #pragma unroll
        for (int i = 0; i < K; ++i) {            // rows (axis=2)
            const float sum = ((p[i*K+0] + p[i*K+1]) + (p[i*K+2] + p[i*K+3]))
                            + (p[i*K+4] + p[i*K+5]);
            const float r = __builtin_amdgcn_rcpf(sum);
            #pragma unroll
            for (int j = 0; j < K; ++j) p[i*K+j] *= r;
        }
        #pragma unroll
        for (int j = 0; j < K; ++j) {            // cols (axis=1)
            const float sum = ((p[0*K+j] + p[1*K+j]) + (p[2*K+j] + p[3*K+j]))
                            + (p[4*K+j] + p[5*K+j]);
            const float r = __builtin_amdgcn_rcpf(sum);
            #pragma unroll
            for (int i = 0; i < K; ++i) p[i*K+j] *= r;
        }
    }

    // ordered[row,i,d] = sum_j P[j,i] * seq[b,j,d]
    float o[K*DF];
    #pragma unroll
    for (int i = 0; i < K*DF; ++i) o[i] = 0.f;

    const float4* s4 = reinterpret_cast<const float4*>(seq + (size_t)b * (K*DF));
    #pragma unroll
    for (int j = 0; j < K; ++j) {
        float4 a0 = s4[j*2 + 0];
        float4 a1 = s4[j*2 + 1];
        float srow[DF] = {a0.x, a0.y, a0.z, a0.w, a1.x, a1.y, a1.z, a1.w};
        #pragma unroll
        for (int i = 0; i < K; ++i) {
            const float pv = p[j*K + i];
            #pragma unroll
            for (int d = 0; d < DF; ++d)
                o[i*DF + d] = fmaf(pv, srow[d], o[i*DF + d]);
        }
    }

    float4* o4 = reinterpret_cast<float4*>(out + row * (K*DF));
    #pragma unroll
    for (int q = 0; q < 12; ++q) {
        float4 v;
        v.x = o[q*4+0]; v.y = o[q*4+1]; v.z = o[q*4+2]; v.w = o[q*4+3];
        o4[q] = v;
    }
}

// ---------------------------------------------------------------------------
// Fallback (round-5 monolithic) if ws_size is too small for exp_la.
// ---------------------------------------------------------------------------
__global__ __launch_bounds__(256) void sink_mono_kernel(
    const float* __restrict__ latent,
    const float* __restrict__ seq,
    const float* __restrict__ noise,
    const float* __restrict__ W_sink,
    const float* __restrict__ b_sink,
    float* __restrict__ out)
{
    const int m = blockIdx.x * 256 + threadIdx.x;
    const int b = (int)((unsigned)m / 5u);
    const int s = m - b * 5;
    const size_t row = (size_t)s * B + b;

    float lat[DLAT];
    const float4* lat4 = reinterpret_cast<const float4*>(latent + (size_t)b * DLAT);
    #pragma unroll
    for (int k = 0; k < 4; ++k) {
        float4 v = lat4[k];
        lat[k*4+0] = v.x; lat[k*4+1] = v.y; lat[k*4+2] = v.z; lat[k*4+3] = v.w;
    }

    float la[KK];
    #pragma unroll
    for (int i = 0; i < KK; ++i) la[i] = b_sink[i];
    #pragma unroll
    for (int k = 0; k < DLAT; ++k) {
        const float lv = lat[k];
        #pragma unroll
        for (int i = 0; i < KK; ++i)
            la[i] = fmaf(lv, W_sink[k*KK + i], la[i]);
    }

    float p[KK];
    {
        const float4* n4 = reinterpret_cast<const float4*>(noise + row * KK);
        #pragma unroll
        for (int q = 0; q < 9; ++q) {
            float4 u = n4[q];
            p[q*4+0] = __expf(la[q*4+0]) * __builtin_amdgcn_rcpf(EPS - __logf(u.x + EPS));
            p[q*4+1] = __expf(la[q*4+1]) * __builtin_amdgcn_rcpf(EPS - __logf(u.y + EPS));
            p[q*4+2] = __expf(la[q*4+2]) * __builtin_amdgcn_rcpf(EPS - __logf(u.z + EPS));
            p[q*4+3] = __expf(la[q*4+3]) * __builtin_amdgcn_rcpf(EPS - __logf(u.w + EPS));
        }
    }

    #pragma unroll
    for (int it = 0; it < 5; ++it) {
        #pragma unroll
        for (int i = 0; i < K; ++i) {
            const float sum = ((p[i*K+0] + p[i*K+1]) + (p[i*K+2] + p[i*K+3]))
                            + (p[i*K+4] + p[i*K+5]);
            const float r = __builtin_amdgcn_rcpf(sum);
            #pragma unroll
            for (int j = 0; j < K; ++j) p[i*K+j] *= r;
        }
        #pragma unroll
        for (int j = 0; j < K; ++j) {
            const float sum = ((p[0*K+j] + p[1*K+j]) + (p[2*K+j] + p[3*K+j]))
                            + (p[4*K+j] + p[5*K+j]);
            const float r = __builtin_amdgcn_rcpf(sum);
            #pragma unroll
            for (int i = 0; i < K; ++i) p[i*K+j] *= r;
        }
    }

    float o[K*DF];
    #pragma unroll
    for (int i = 0; i < K*DF; ++i) o[i] = 0.f;
    const float4* s4 = reinterpret_cast<const float4*>(seq + (size_t)b * (K*DF));
    #pragma unroll
    for (int j = 0; j < K; ++j) {
        float4 a0 = s4[j*2 + 0];
        float4 a1 = s4[j*2 + 1];
        float srow[DF] = {a0.x, a0.y, a0.z, a0.w, a1.x, a1.y, a1.z, a1.w};
        #pragma unroll
        for (int i = 0; i < K; ++i) {
            const float pv = p[j*K + i];
            #pragma unroll
            for (int d = 0; d < DF; ++d)
                o[i*DF + d] = fmaf(pv, srow[d], o[i*DF + d]);
        }
    }
    float4* o4 = reinterpret_cast<float4*>(out + row * (K*DF));
    #pragma unroll
    for (int q = 0; q < 12; ++q) {
        float4 v;
        v.x = o[q*4+0]; v.y = o[q*4+1]; v.z = o[q*4+2]; v.w = o[q*4+3];
        o4[q] = v;
    }
}

__global__ __launch_bounds__(256) void mask_kernel(
    const float* __restrict__ latent,
    const float* __restrict__ W_mask,
    const float* __restrict__ b_mask,
    float* __restrict__ outp)
{
    const int b = blockIdx.x * 256 + threadIdx.x;
    if (b >= B) return;

    float lat[DLAT];
    const float4* lat4 = reinterpret_cast<const float4*>(latent + (size_t)b * DLAT);
    #pragma unroll
    for (int k = 0; k < 4; ++k) {
        float4 v = lat4[k];
        lat[k*4+0] = v.x; lat[k*4+1] = v.y; lat[k*4+2] = v.z; lat[k*4+3] = v.w;
    }
    float v[K];
    #pragma unroll
    for (int i = 0; i < K; ++i) v[i] = b_mask[i];
    #pragma unroll
    for (int k = 0; k < DLAT; ++k) {
        const float lv = lat[k];
        #pragma unroll
        for (int i = 0; i < K; ++i)
            v[i] = fmaf(lv, W_mask[k*K + i], v[i]);
    }
    float mx = v[0];
    #pragma unroll
    for (int i = 1; i < K; ++i) mx = fmaxf(mx, v[i]);
    float sum = 0.f;
    #pragma unroll
    for (int i = 0; i < K; ++i) { v[i] = __expf(v[i] - mx); sum += v[i]; }
    const float inv = 1.f / sum;
    float2* o2 = reinterpret_cast<float2*>(outp + (size_t)b * K);
    o2[0] = make_float2(v[0]*inv, v[1]*inv);
    o2[1] = make_float2(v[2]*inv, v[3]*inv);
    o2[2] = make_float2(v[4]*inv, v[5]*inv);
}

} // namespace

extern "C" void kernel_launch(void* const* d_in, const int* in_sizes, int n_in,
                              void* d_out, int out_size, void* d_ws, size_t ws_size,
                              hipStream_t stream) {
    const float* latent = (const float*)d_in[0];
    const float* seq    = (const float*)d_in[1];
    const float* noise  = (const float*)d_in[2];
    const float* W_sink = (const float*)d_in[3];
    const float* b_sink = (const float*)d_in[4];
    const float* W_mask = (const float*)d_in[5];
    const float* b_mask = (const float*)d_in[6];
    float* out      = (float*)d_out;
    float* stopping = out + (size_t)M * K * DF;

    const size_t need = (size_t)B * KK * sizeof(float);   // 18.9 MB
    if (ws_size >= need) {
        float* ela = (float*)d_ws;
        prep_kernel<<<B / 256, 256, 0, stream>>>(latent, W_sink, b_sink,
                                                 W_mask, b_mask, ela, stopping);
        sink_kernel<<<M / 256, 256, 0, stream>>>(seq, noise, ela, out);
    } else {
        sink_mono_kernel<<<M / 256, 256, 0, stream>>>(latent, seq, noise,
                                                      W_sink, b_sink, out);
        mask_kernel<<<B / 256, 256, 0, stream>>>(latent, W_mask, b_mask, stopping);
    }
}

// Round 7
// 94.554 us; speedup vs baseline: 1.0687x; 1.0687x over previous
//
#include <hip/hip_runtime.h>

namespace {

constexpr int K     = 6;
constexpr int KK    = 36;   // K*K
constexpr int DF    = 8;    // D_FEAT
constexpr int DLAT  = 16;
constexpr int NS    = 5;
constexpr int B     = 131072;
constexpr int M     = NS * B;           // 655360 output rows of [K,DF]
constexpr float EPS = 1e-20f;

// One thread per batch element b; loops over the 5 samples in-registers.
//  - latent@W_sink matvec (576 FMA) + exp() once per b (not 5x)
//  - seq[48] held in registers across samples (one read per b)
//  - masknet fused (latent already live)
//  - exp-domain Sinkhorn: P = ela * rcp(EPS - log(u+EPS)); 5x row/col
//    sum-normalize == reference's log-domain logsumexp exactly (bounded
//    values, f32-safe; validated rounds 5/6, absmax 7.8e-3)
__global__ __launch_bounds__(256) void fused_kernel(
    const float* __restrict__ latent,
    const float* __restrict__ seq,
    const float* __restrict__ noise,
    const float* __restrict__ W_sink,
    const float* __restrict__ b_sink,
    const float* __restrict__ W_mask,
    const float* __restrict__ b_mask,
    float* __restrict__ out,        // [NS*B][K*DF]
    float* __restrict__ stopping)   // [B][K]
{
    const int b = blockIdx.x * 256 + threadIdx.x;   // grid is exactly B/256

    // ---- latent[b][0..15], coalesced (lane-consecutive rows of 64 B) ----
    float lat[DLAT];
    const float4* lat4 = reinterpret_cast<const float4*>(latent + (size_t)b * DLAT);
    #pragma unroll
    for (int k = 0; k < 4; ++k) {
        float4 v = lat4[k];
        lat[k*4+0] = v.x; lat[k*4+1] = v.y; lat[k*4+2] = v.z; lat[k*4+3] = v.w;
    }

    // ---- sinknet matvec, once per b; W/b wave-uniform -> scalar loads ----
    float ela[KK];
    #pragma unroll
    for (int i = 0; i < KK; ++i) ela[i] = b_sink[i];
    #pragma unroll
    for (int k = 0; k < DLAT; ++k) {
        const float lv = lat[k];
        #pragma unroll
        for (int i = 0; i < KK; ++i)
            ela[i] = fmaf(lv, W_sink[k*KK + i], ela[i]);
    }

    // ---- masknet (latent still live), then release lat ----
    {
        float v[K];
        #pragma unroll
        for (int i = 0; i < K; ++i) v[i] = b_mask[i];
        #pragma unroll
        for (int k = 0; k < DLAT; ++k) {
            const float lv = lat[k];
            #pragma unroll
            for (int i = 0; i < K; ++i)
                v[i] = fmaf(lv, W_mask[k*K + i], v[i]);
        }
        float mx = v[0];
        #pragma unroll
        for (int i = 1; i < K; ++i) mx = fmaxf(mx, v[i]);
        float sum = 0.f;
        #pragma unroll
        for (int i = 0; i < K; ++i) { v[i] = __expf(v[i] - mx); sum += v[i]; }
        const float inv = __builtin_amdgcn_rcpf(sum);
        float2* o2 = reinterpret_cast<float2*>(stopping + (size_t)b * K);
        o2[0] = make_float2(v[0]*inv, v[1]*inv);
        o2[1] = make_float2(v[2]*inv, v[3]*inv);
        o2[2] = make_float2(v[4]*inv, v[5]*inv);
    }

    // ---- exp of log_alpha, once per b ----
    #pragma unroll
    for (int i = 0; i < KK; ++i) ela[i] = __expf(ela[i]);

    // ---- seq[b][6][8] -> registers, kept across all 5 samples ----
    float sq[K*DF];
    const float4* s4 = reinterpret_cast<const float4*>(seq + (size_t)b * (K*DF));
    #pragma unroll
    for (int q = 0; q < 12; ++q) {
        float4 v = s4[q];
        sq[q*4+0] = v.x; sq[q*4+1] = v.y; sq[q*4+2] = v.z; sq[q*4+3] = v.w;
    }

    // ---- 5 samples: gumbel-perturb, Sinkhorn, P^T @ seq, store ----
    #pragma unroll
    for (int s = 0; s < NS; ++s) {
        const size_t row = (size_t)s * B + b;

        float p[KK];
        {
            const float4* n4 = reinterpret_cast<const float4*>(noise + row * KK);
            #pragma unroll
            for (int q = 0; q < 9; ++q) {
                float4 u = n4[q];
                p[q*4+0] = ela[q*4+0] * __builtin_amdgcn_rcpf(EPS - __logf(u.x + EPS));
                p[q*4+1] = ela[q*4+1] * __builtin_amdgcn_rcpf(EPS - __logf(u.y + EPS));
                p[q*4+2] = ela[q*4+2] * __builtin_amdgcn_rcpf(EPS - __logf(u.z + EPS));
                p[q*4+3] = ela[q*4+3] * __builtin_amdgcn_rcpf(EPS - __logf(u.w + EPS));
            }
        }

        #pragma unroll
        for (int it = 0; it < 5; ++it) {
            #pragma unroll
            for (int i = 0; i < K; ++i) {            // rows (axis=2)
                const float sum = ((p[i*K+0] + p[i*K+1]) + (p[i*K+2] + p[i*K+3]))
                                + (p[i*K+4] + p[i*K+5]);
                const float r = __builtin_amdgcn_rcpf(sum);
                #pragma unroll
                for (int j = 0; j < K; ++j) p[i*K+j] *= r;
            }
            #pragma unroll
            for (int j = 0; j < K; ++j) {            // cols (axis=1)
                const float sum = ((p[0*K+j] + p[1*K+j]) + (p[2*K+j] + p[3*K+j]))
                                + (p[4*K+j] + p[5*K+j]);
                const float r = __builtin_amdgcn_rcpf(sum);
                #pragma unroll
                for (int i = 0; i < K; ++i) p[i*K+j] *= r;
            }
        }

        // ordered[row,i,:] = sum_j P[j,i] * sq[j,:]  — streamed row by row
        float4* o4 = reinterpret_cast<float4*>(out + row * (K*DF));
        #pragma unroll
        for (int i = 0; i < K; ++i) {
            float orow[DF];
            #pragma unroll
            for (int d = 0; d < DF; ++d) orow[d] = 0.f;
            #pragma unroll
            for (int j = 0; j < K; ++j) {
                const float pv = p[j*K + i];
                #pragma unroll
                for (int d = 0; d < DF; ++d)
                    orow[d] = fmaf(pv, sq[j*DF + d], orow[d]);
            }
            float4 v0, v1;
            v0.x = orow[0]; v0.y = orow[1]; v0.z = orow[2]; v0.w = orow[3];
            v1.x = orow[4]; v1.y = orow[5]; v1.z = orow[6]; v1.w = orow[7];
            o4[i*2 + 0] = v0;
            o4[i*2 + 1] = v1;
        }
    }
}

} // namespace

extern "C" void kernel_launch(void* const* d_in, const int* in_sizes, int n_in,
                              void* d_out, int out_size, void* d_ws, size_t ws_size,
                              hipStream_t stream) {
    const float* latent = (const float*)d_in[0];
    const float* seq    = (const float*)d_in[1];
    const float* noise  = (const float*)d_in[2];
    const float* W_sink = (const float*)d_in[3];
    const float* b_sink = (const float*)d_in[4];
    const float* W_mask = (const float*)d_in[5];
    const float* b_mask = (const float*)d_in[6];
    float* out      = (float*)d_out;
    float* stopping = out + (size_t)M * K * DF;

    fused_kernel<<<B / 256, 256, 0, stream>>>(latent, seq, noise,
                                              W_sink, b_sink, W_mask, b_mask,
                                              out, stopping);
}